// Round 2
// baseline (611.891 us; speedup 1.0000x reference)
//
#include <hip/hip_runtime.h>
#include <hip/hip_bf16.h>

typedef __attribute__((ext_vector_type(8))) short bf16x8;
typedef __attribute__((ext_vector_type(4))) float f32x4;
typedef unsigned short u16;

#define MFMA16(a,b,c) __builtin_amdgcn_mfma_f32_16x16x32_bf16((a),(b),(c),0,0,0)
#define FENCE() asm volatile("" ::: "memory")
#define BARRIER() do { FENCE(); __builtin_amdgcn_s_barrier(); FENCE(); } while (0)
#define WAITV(N) asm volatile("s_waitcnt vmcnt(" #N ")" ::: "memory")
#define WAITLGKM0() do { asm volatile("s_waitcnt lgkmcnt(0)" ::: "memory"); \
                         __builtin_amdgcn_sched_barrier(0); } while (0)

__device__ __forceinline__ u16 f2bf(float f) {
  union { float f; unsigned int u; } c; c.f = f;
  unsigned int u = c.u;
  return (u16)((u + 0x7FFFu + ((u >> 16) & 1u)) >> 16);
}

__device__ __forceinline__ void gl_lds16(const u16* g, u16* l) {
  __builtin_amdgcn_global_load_lds((const __attribute__((address_space(1))) void*)g,
                                   (__attribute__((address_space(3))) void*)l, 16, 0, 0);
}

// ---------------- X fp32 -> bf16 ----------------
__global__ __launch_bounds__(256) void convert_x(const float* __restrict__ X,
                                                 u16* __restrict__ Xb) {
  int i = (blockIdx.x * 256 + threadIdx.x) * 8;
  const float4* p = (const float4*)(X + i);
  float4 a = p[0], b = p[1];
  union { u16 h[8]; uint4 v; } o;
  o.h[0] = f2bf(a.x); o.h[1] = f2bf(a.y); o.h[2] = f2bf(a.z); o.h[3] = f2bf(a.w);
  o.h[4] = f2bf(b.x); o.h[5] = f2bf(b.y); o.h[6] = f2bf(b.z); o.h[7] = f2bf(b.w);
  *(uint4*)(Xb + i) = o.v;
}

// ---------------- W [k][n] fp32 -> WT [n][k] bf16 ----------------
__global__ __launch_bounds__(256) void transpose_w(const float* __restrict__ W,
                                                   u16* __restrict__ WT) {
  __shared__ float t[32][33];
  int n0 = blockIdx.x * 32, k0 = blockIdx.y * 32;
  int tx = threadIdx.x, ty = threadIdx.y; // 32 x 8
#pragma unroll
  for (int i = 0; i < 4; ++i)
    t[ty + i * 8][tx] = W[(size_t)(k0 + ty + i * 8) * 768 + n0 + tx];
  __syncthreads();
#pragma unroll
  for (int i = 0; i < 4; ++i)
    WT[(size_t)(n0 + ty + i * 8) * 768 + k0 + tx] = f2bf(t[tx][ty + i * 8]);
}

// ---------------- GEMM 256x256, BK=64, 8 waves, 4-phase pipelined ----------------
// C[m][n] = sum_k A[m][k] * BT[n][k] (+bias)
// MODE 0: QKV (N=2304): Q bf16 (scaled 1/8), K bf16, V bf16 transposed per (b,h)
// MODE 1: out-proj (N=768): fp32 + bias
// LDS tiles [256][64] bf16, 16B-granule XOR swizzle: granule (row,sg) holds
// global col-block sg^(row&7); reads XOR the same way (rule #21: linear LDS
// dest for global_load_lds + inverse-swizzled global source + swizzled read).

#define STAGE_A(bb, kt, mh) do { \
  _Pragma("unroll") for (int j_ = 0; j_ < 2; ++j_) { \
    const int R0_ = (mh) * 64 + j_ * 128; \
    const int row_ = R0_ + wave * 8 + (lane >> 3); \
    gl_lds16(A + (size_t)(M0 + row_) * 768 + (kt) * 64 + cbx * 8, \
             &As[bb][R0_ * 64 + wave * 512 + lane * 8]); \
  } } while (0)

#define STAGE_B(bb, kt, nh) do { \
  _Pragma("unroll") for (int j_ = 0; j_ < 2; ++j_) { \
    const int R0_ = (j_ * 2 + (wave >> 2)) * 64 + (nh) * 32; \
    const int row_ = R0_ + (wave & 3) * 8 + (lane >> 3); \
    gl_lds16(BT + (size_t)(N0 + row_) * 768 + (kt) * 64 + cbx * 8, \
             &Bs[bb][R0_ * 64 + (wave & 3) * 512 + lane * 8]); \
  } } while (0)

#define PHASE(bb, mh, nh, STAGECODE, WAITCODE) do { \
  bf16x8 af_[4][2], bf_[2][2]; \
  _Pragma("unroll") for (int mt_ = 0; mt_ < 4; ++mt_) \
    _Pragma("unroll") for (int kh_ = 0; kh_ < 2; ++kh_) { \
      const int row_ = wr * 128 + (mh) * 64 + mt_ * 16 + l15; \
      af_[mt_][kh_] = *(const bf16x8*)&As[bb][row_ * 64 + (((kh_ * 4 + lg) ^ (l15 & 7)) << 3)]; \
    } \
  _Pragma("unroll") for (int nt_ = 0; nt_ < 2; ++nt_) \
    _Pragma("unroll") for (int kh_ = 0; kh_ < 2; ++kh_) { \
      const int row_ = wc * 64 + (nh) * 32 + nt_ * 16 + l15; \
      bf_[nt_][kh_] = *(const bf16x8*)&Bs[bb][row_ * 64 + (((kh_ * 4 + lg) ^ (l15 & 7)) << 3)]; \
    } \
  STAGECODE; \
  BARRIER(); \
  WAITLGKM0(); \
  __builtin_amdgcn_s_setprio(1); \
  _Pragma("unroll") for (int mt_ = 0; mt_ < 4; ++mt_) \
    _Pragma("unroll") for (int nt_ = 0; nt_ < 2; ++nt_) \
      _Pragma("unroll") for (int kh_ = 0; kh_ < 2; ++kh_) \
        acc[(mh) * 4 + mt_][(nh) * 2 + nt_] = \
            MFMA16(af_[mt_][kh_], bf_[nt_][kh_], acc[(mh) * 4 + mt_][(nh) * 2 + nt_]); \
  __builtin_amdgcn_s_setprio(0); \
  WAITCODE; \
  BARRIER(); \
} while (0)

template <int MODE>
__global__ __launch_bounds__(512, 2)
void gemm8(const u16* __restrict__ A, const u16* __restrict__ BT,
           const float* __restrict__ b0, const float* __restrict__ b1,
           const float* __restrict__ b2,
           u16* __restrict__ oQ, u16* __restrict__ oK, u16* __restrict__ oV,
           float* __restrict__ oF, int NT) {
  __shared__ __align__(16) u16 As[2][16384];
  __shared__ __align__(16) u16 Bs[2][16384];
  const int tid = threadIdx.x;
  const int wave = tid >> 6, lane = tid & 63;
  const int lg = lane >> 4, l15 = lane & 15;
  const int wr = wave >> 2, wc = wave & 3;
  const int M0 = blockIdx.x * 256, N0 = blockIdx.y * 256;
  const int cbx = (lane & 7) ^ ((lane >> 3) & 7);

  f32x4 acc[8][4] = {};

  // prologue: stage tile 0 into buffer 0, drain, barrier
  STAGE_A(0, 0, 0); STAGE_B(0, 0, 0); STAGE_B(0, 0, 1); STAGE_A(0, 0, 1);
  WAITV(0);
  BARRIER();

  for (int t = 0; t < NT; ++t) {
    const int bb = t & 1, nb = bb ^ 1;
    if (t + 1 < NT) {
      PHASE(bb, 0, 0, STAGE_A(nb, t + 1, 0), WAITV(4));
      PHASE(bb, 0, 1, STAGE_B(nb, t + 1, 0), WAITV(4));
      PHASE(bb, 1, 0, STAGE_B(nb, t + 1, 1), (void)0);
      PHASE(bb, 1, 1, STAGE_A(nb, t + 1, 1), WAITV(4));
    } else {
      PHASE(bb, 0, 0, (void)0, WAITV(2));
      PHASE(bb, 0, 1, (void)0, WAITV(0));
      PHASE(bb, 1, 0, (void)0, (void)0);
      PHASE(bb, 1, 1, (void)0, (void)0);
    }
  }

  // epilogue
#pragma unroll
  for (int mi = 0; mi < 8; ++mi) {
    const int r0 = M0 + wr * 128 + mi * 16 + lg * 4;
#pragma unroll
    for (int ni = 0; ni < 4; ++ni) {
      const int ng = N0 + wc * 64 + ni * 16 + l15;
      f32x4 v = acc[mi][ni];
      if (MODE == 1) {
        const float bb = b0[ng];
#pragma unroll
        for (int r = 0; r < 4; ++r)
          oF[(size_t)(r0 + r) * 768 + ng] = v[r] + bb;
      } else {
        const int mat = ng / 768;
        const int col = ng - mat * 768;
        const float bb = (mat == 0 ? b0 : (mat == 1 ? b1 : b2))[col];
        if (mat == 0) {
#pragma unroll
          for (int r = 0; r < 4; ++r)
            oQ[(size_t)(r0 + r) * 768 + col] = f2bf((v[r] + bb) * 0.125f);
        } else if (mat == 1) {
#pragma unroll
          for (int r = 0; r < 4; ++r)
            oK[(size_t)(r0 + r) * 768 + col] = f2bf(v[r] + bb);
        } else {
          const int hh = col >> 6, dd = col & 63;
#pragma unroll
          for (int r = 0; r < 4; ++r) {
            const int rr = r0 + r;
            const int bbx = rr >> 9, ss = rr & 511;
            oV[((size_t)(bbx * 12 + hh) * 64 + dd) * 512 + ss] = f2bf(v[r] + bb);
          }
        }
      }
    }
  }
}

// ---------------- causal flash attention (double-buffered, swizzled K/V) ----
// grid: (qt=8, h=12, b=32); 256 threads = 4 waves; wave handles 16 q-rows.
// Q: [16384][768] bf16 (pre-scaled). K: [16384][768]. V: [b*12+h][64][512].
// K/V tiles in LDS as [64][64] bf16 with the same granule XOR swizzle.
__global__ __launch_bounds__(256)
void flash(const u16* __restrict__ Q, const u16* __restrict__ K,
           const u16* __restrict__ V, u16* __restrict__ O) {
  __shared__ __align__(16) u16 Ks[2][4096]; // [64 key][64 d] swizzled
  __shared__ __align__(16) u16 Vs[2][4096]; // [64 d][64 key] swizzled
  __shared__ __align__(16) u16 Ps[4][1024]; // per wave [2 k-half][16 r][32 key']
  const int qt = blockIdx.x, h = blockIdx.y, b = blockIdx.z;
  const int tid = threadIdx.x, wave = tid >> 6, lane = tid & 63;
  const int lg = lane >> 4, l15 = lane & 15;
  const int cbx = (lane & 7) ^ ((lane >> 3) & 7);
  bf16x8 qf[2];
  {
    const u16* qp = Q + (size_t)(b * 512 + qt * 64 + wave * 16 + l15) * 768 + h * 64 + lg * 8;
    qf[0] = *(const bf16x8*)qp;
    qf[1] = *(const bf16x8*)(qp + 32);
  }
  f32x4 oacc[4] = {};
  float m_run[4], l_run[4];
#pragma unroll
  for (int r = 0; r < 4; ++r) { m_run[r] = -1e30f; l_run[r] = 0.f; }
  const u16* Kg0 = K + (size_t)(b * 512) * 768 + h * 64;
  const u16* Vg0 = V + (size_t)(b * 12 + h) * 64 * 512;
  u16* pw = Ps[wave];

#define STAGE_KV(bb, kt) do { \
  _Pragma("unroll") for (int j_ = 0; j_ < 2; ++j_) { \
    const int row_ = j_ * 32 + wave * 8 + (lane >> 3); \
    const int go_ = (j_ * 256 + wave * 64 + lane) * 8; \
    gl_lds16(Kg0 + (size_t)((kt) * 64 + row_) * 768 + cbx * 8, &Ks[bb][go_]); \
    gl_lds16(Vg0 + (size_t)row_ * 512 + (kt) * 64 + cbx * 8, &Vs[bb][go_]); \
  } } while (0)

  STAGE_KV(0, 0);
  for (int kt = 0; kt <= qt; ++kt) {
    const int bb = kt & 1;
    if (kt < qt) { STAGE_KV(bb ^ 1, kt + 1); WAITV(4); }
    else         { WAITV(0); }
    BARRIER();
    // QK^T
    f32x4 sc[4] = {};
#pragma unroll
    for (int kc = 0; kc < 2; ++kc) {
#pragma unroll
      for (int t = 0; t < 4; ++t) {
        const int row = t * 16 + l15;
        bf16x8 kf = *(const bf16x8*)&Ks[bb][row * 64 + (((kc * 4 + lg) ^ (l15 & 7)) << 3)];
        sc[t] = MFMA16(qf[kc], kf, sc[t]);
      }
    }
    if (kt == qt) { // diagonal tile: causal mask
#pragma unroll
      for (int t = 0; t < 4; ++t)
#pragma unroll
        for (int r = 0; r < 4; ++r)
          if (t * 16 + l15 > wave * 16 + lg * 4 + r) sc[t][r] = -1e30f;
    }
    // online softmax (row groups of 16 lanes)
    float mx[4], fs[4], rs[4];
#pragma unroll
    for (int r = 0; r < 4; ++r) {
      float m = fmaxf(fmaxf(sc[0][r], sc[1][r]), fmaxf(sc[2][r], sc[3][r]));
      m = fmaxf(m, __shfl_xor(m, 1));
      m = fmaxf(m, __shfl_xor(m, 2));
      m = fmaxf(m, __shfl_xor(m, 4));
      m = fmaxf(m, __shfl_xor(m, 8));
      float mn = fmaxf(m_run[r], m);
      fs[r] = __expf(m_run[r] - mn);
      m_run[r] = mn;
      mx[r] = mn;
      rs[r] = 0.f;
    }
    u16 pb[4][4];
#pragma unroll
    for (int t = 0; t < 4; ++t)
#pragma unroll
      for (int r = 0; r < 4; ++r) {
        float p = __expf(sc[t][r] - mx[r]);
        rs[r] += p;
        pb[t][r] = f2bf(p);
      }
#pragma unroll
    for (int r = 0; r < 4; ++r) {
      rs[r] += __shfl_xor(rs[r], 1);
      rs[r] += __shfl_xor(rs[r], 2);
      rs[r] += __shfl_xor(rs[r], 4);
      rs[r] += __shfl_xor(rs[r], 8);
      l_run[r] = l_run[r] * fs[r] + rs[r];
    }
#pragma unroll
    for (int t = 0; t < 4; ++t)
#pragma unroll
      for (int r = 0; r < 4; ++r)
        oacc[t][r] *= fs[r];
    // stage P (per-wave LDS region)
#pragma unroll
    for (int t = 0; t < 4; ++t)
#pragma unroll
      for (int r = 0; r < 4; ++r)
        pw[(t >> 1) * 512 + (lg * 4 + r) * 32 + (t & 1) * 16 + l15] = pb[t][r];
    // PV
#pragma unroll
    for (int kc = 0; kc < 2; ++kc) {
      bf16x8 pf = *(const bf16x8*)(pw + kc * 512 + l15 * 32 + lg * 8);
#pragma unroll
      for (int t = 0; t < 4; ++t) {
        const int row = t * 16 + l15;
        bf16x8 vf = *(const bf16x8*)&Vs[bb][row * 64 + (((kc * 4 + lg) ^ (l15 & 7)) << 3)];
        oacc[t] = MFMA16(pf, vf, oacc[t]);
      }
    }
    BARRIER(); // exit: all reads of this buffer done before next stage overwrites
  }
#pragma unroll
  for (int r = 0; r < 4; ++r) {
    float inv = 1.f / l_run[r];
#pragma unroll
    for (int t = 0; t < 4; ++t)
      O[(size_t)(b * 512 + qt * 64 + wave * 16 + lg * 4 + r) * 768 + h * 64 + t * 16 + l15] =
          f2bf(oacc[t][r] * inv);
  }
}

extern "C" void kernel_launch(void* const* d_in, const int* in_sizes, int n_in,
                              void* d_out, int out_size, void* d_ws, size_t ws_size,
                              hipStream_t stream) {
  (void)in_sizes; (void)n_in; (void)out_size; (void)ws_size;
  const float* X  = (const float*)d_in[0];
  // d_in[1] = causal mask: exactly triu(-1e9) -> equivalent to hard causal masking; unused.
  const float* Wq = (const float*)d_in[2];
  const float* bq = (const float*)d_in[3];
  const float* Wk = (const float*)d_in[4];
  const float* bk = (const float*)d_in[5];
  const float* Wv = (const float*)d_in[6];
  const float* bv = (const float*)d_in[7];
  const float* Wo = (const float*)d_in[8];
  const float* bo = (const float*)d_in[9];
  float* out = (float*)d_out;

  const size_t NME = (size_t)16384 * 768;
  u16* Xb  = (u16*)d_ws;        // bf16 X, later reused as attention output
  u16* Qs  = Xb + NME;
  u16* Kb  = Qs + NME;
  u16* Vt  = Kb + NME;          // [b*12+h][64][512]
  u16* WT  = Vt + NME;          // [2304][768]  (WqT | WkT | WvT)
  u16* WoT = WT + (size_t)2304 * 768;
  u16* Ao  = Xb;

  convert_x<<<6144, 256, 0, stream>>>(X, Xb);
  dim3 tb(32, 8);
  transpose_w<<<dim3(24, 24), tb, 0, stream>>>(Wq, WT);
  transpose_w<<<dim3(24, 24), tb, 0, stream>>>(Wk, WT + (size_t)768 * 768);
  transpose_w<<<dim3(24, 24), tb, 0, stream>>>(Wv, WT + (size_t)2 * 768 * 768);
  transpose_w<<<dim3(24, 24), tb, 0, stream>>>(Wo, WoT);
  gemm8<0><<<dim3(64, 9), 512, 0, stream>>>(Xb, WT, bq, bk, bv, Qs, Kb, Vt, nullptr, 12);
  flash<<<dim3(8, 12, 32), 256, 0, stream>>>(Qs, Kb, Vt, Ao);
  gemm8<1><<<dim3(64, 3), 512, 0, stream>>>(Ao, WoT, bo, nullptr, nullptr,
                                            nullptr, nullptr, nullptr, out, 12);
}

// Round 3
// 228.828 us; speedup vs baseline: 2.6740x; 2.6740x over previous
//
#include <hip/hip_runtime.h>
#include <hip/hip_bf16.h>

typedef __attribute__((ext_vector_type(8))) short bf16x8;
typedef __attribute__((ext_vector_type(4))) float f32x4;
typedef unsigned short u16;

#define MFMA16(a,b,c) __builtin_amdgcn_mfma_f32_16x16x32_bf16((a),(b),(c),0,0,0)
#define FENCE() asm volatile("" ::: "memory")
#define BARRIER() do { FENCE(); __builtin_amdgcn_s_barrier(); FENCE(); } while (0)
#define WAITV(N) asm volatile("s_waitcnt vmcnt(" #N ")" ::: "memory")

__device__ __forceinline__ u16 f2bf(float f) {
  union { float f; unsigned int u; } c; c.f = f;
  unsigned int u = c.u;
  return (u16)((u + 0x7FFFu + ((u >> 16) & 1u)) >> 16);
}

__device__ __forceinline__ void gl_lds16(const u16* g, u16* l) {
  __builtin_amdgcn_global_load_lds((const __attribute__((address_space(1))) void*)g,
                                   (__attribute__((address_space(3))) void*)l, 16, 0, 0);
}

// ---------------- X fp32 -> bf16 ----------------
__global__ __launch_bounds__(256) void convert_x(const float* __restrict__ X,
                                                 u16* __restrict__ Xb) {
  int i = (blockIdx.x * 256 + threadIdx.x) * 8;
  const float4* p = (const float4*)(X + i);
  float4 a = p[0], b = p[1];
  union { u16 h[8]; uint4 v; } o;
  o.h[0] = f2bf(a.x); o.h[1] = f2bf(a.y); o.h[2] = f2bf(a.z); o.h[3] = f2bf(a.w);
  o.h[4] = f2bf(b.x); o.h[5] = f2bf(b.y); o.h[6] = f2bf(b.z); o.h[7] = f2bf(b.w);
  *(uint4*)(Xb + i) = o.v;
}

// ---------------- W [k][n] fp32 -> WT [n][k] bf16 ----------------
__global__ __launch_bounds__(256) void transpose_w(const float* __restrict__ W,
                                                   u16* __restrict__ WT) {
  __shared__ float t[32][33];
  int n0 = blockIdx.x * 32, k0 = blockIdx.y * 32;
  int tx = threadIdx.x, ty = threadIdx.y; // 32 x 8
#pragma unroll
  for (int i = 0; i < 4; ++i)
    t[ty + i * 8][tx] = W[(size_t)(k0 + ty + i * 8) * 768 + n0 + tx];
  __syncthreads();
#pragma unroll
  for (int i = 0; i < 4; ++i)
    WT[(size_t)(n0 + ty + i * 8) * 768 + k0 + tx] = f2bf(t[tx][ty + i * 8]);
}

// ---------------- GEMM 128x256, BK=64, 8 waves, 3-buffer 2-deep pipeline ----
// C[m][n] = sum_k A[m][k] * BT[n][k] (+bias)
// MODE 0: QKV (N=2304): Q bf16 (scaled 1/8), K bf16, V bf16 transposed per (b,h)
// MODE 1: out-proj (N=768): fp32 + bias
// LDS rows = 64 bf16 (128B) = 8 granules of 16B; granule g of row r holds
// global granule g^(r&7) (rule #21: linear gl_lds dest + inverse-swizzled
// global source + swizzled read). One barrier + one counted vmcnt per K-tile.

#define STA(bu, t) do { _Pragma("unroll") for (int s_ = 0; s_ < 2; ++s_) { \
    const int r_ = s_ * 64 + srow; \
    gl_lds16(A + (size_t)(M0 + r_) * 768 + (t) * 64 + ((sg ^ (r_ & 7)) << 3), \
             &As[bu][r_ * 64 + sg * 8]); } } while (0)
#define STB(bu, t) do { _Pragma("unroll") for (int s_ = 0; s_ < 4; ++s_) { \
    const int r_ = s_ * 64 + srow; \
    gl_lds16(BT + (size_t)(N0 + r_) * 768 + (t) * 64 + ((sg ^ (r_ & 7)) << 3), \
             &Bs[bu][r_ * 64 + sg * 8]); } } while (0)

template <int MODE>
__global__ __launch_bounds__(512, 2)
void gemmP(const u16* __restrict__ A, const u16* __restrict__ BT,
           const float* __restrict__ b0, const float* __restrict__ b1,
           const float* __restrict__ b2,
           u16* __restrict__ oQ, u16* __restrict__ oK, u16* __restrict__ oV,
           float* __restrict__ oF) {
  constexpr int NT = 12; // K = 768 = 12 * 64
  __shared__ __align__(16) u16 As[3][128 * 64];
  __shared__ __align__(16) u16 Bs[3][256 * 64];
  const int tid = threadIdx.x;
  const int wave = tid >> 6, lane = tid & 63;
  const int lg = lane >> 4, l15 = lane & 15;
  const int wr = wave >> 2, wc = wave & 3;
  const int M0 = blockIdx.x * 128, N0 = blockIdx.y * 256;
  const int srow = tid >> 3, sg = tid & 7;

  f32x4 acc[4][4] = {};

  // 2-deep prologue
  STA(0, 0); STB(0, 0);
  STA(1, 1); STB(1, 1);

#pragma unroll
  for (int t = 0; t < NT; ++t) {
    if (t < NT - 1) { WAITV(6); } else { WAITV(0); }
    BARRIER(); // buf[t%3] ready for all waves; buf[(t+2)%3] == buf[(t-1)%3] free
    if (t + 2 < NT) {
      STA((t + 2) % 3, t + 2);
      STB((t + 2) % 3, t + 2);
    }
    const int bb = t % 3;
    __builtin_amdgcn_s_setprio(1);
    bf16x8 bfr[4][2];
#pragma unroll
    for (int nt = 0; nt < 4; ++nt)
#pragma unroll
      for (int kh = 0; kh < 2; ++kh) {
        const int row = wc * 64 + nt * 16 + l15;
        bfr[nt][kh] = *(const bf16x8*)&Bs[bb][row * 64 + (((kh * 4 + lg) ^ (row & 7)) << 3)];
      }
#pragma unroll
    for (int mt = 0; mt < 4; ++mt) {
      bf16x8 af[2];
#pragma unroll
      for (int kh = 0; kh < 2; ++kh) {
        const int row = wr * 64 + mt * 16 + l15;
        af[kh] = *(const bf16x8*)&As[bb][row * 64 + (((kh * 4 + lg) ^ (row & 7)) << 3)];
      }
#pragma unroll
      for (int nt = 0; nt < 4; ++nt)
#pragma unroll
        for (int kh = 0; kh < 2; ++kh)
          acc[mt][nt] = MFMA16(af[kh], bfr[nt][kh], acc[mt][nt]);
    }
    __builtin_amdgcn_s_setprio(0);
  }

  // epilogue
#pragma unroll
  for (int mt = 0; mt < 4; ++mt) {
    const int r0 = M0 + wr * 64 + mt * 16 + lg * 4;
#pragma unroll
    for (int nt = 0; nt < 4; ++nt) {
      const int ng = N0 + wc * 64 + nt * 16 + l15;
      f32x4 v = acc[mt][nt];
      if (MODE == 1) {
        const float bb = b0[ng];
#pragma unroll
      for (int r = 0; r < 4; ++r)
          oF[(size_t)(r0 + r) * 768 + ng] = v[r] + bb;
      } else {
        const int mat = ng / 768;
        const int col = ng - mat * 768;
        const float bb = (mat == 0 ? b0 : (mat == 1 ? b1 : b2))[col];
        if (mat == 0) {
#pragma unroll
          for (int r = 0; r < 4; ++r)
            oQ[(size_t)(r0 + r) * 768 + col] = f2bf((v[r] + bb) * 0.125f);
        } else if (mat == 1) {
#pragma unroll
          for (int r = 0; r < 4; ++r)
            oK[(size_t)(r0 + r) * 768 + col] = f2bf(v[r] + bb);
        } else {
          const int hh = col >> 6, dd = col & 63;
#pragma unroll
          for (int r = 0; r < 4; ++r) {
            const int rr = r0 + r;
            const int bbx = rr >> 9, ss = rr & 511;
            oV[((size_t)(bbx * 12 + hh) * 64 + dd) * 512 + ss] = f2bf(v[r] + bb);
          }
        }
      }
    }
  }
}

// ---------------- causal flash attention (double-buffered, swizzled K/V) ----
// grid: (qt=8, h=12, b=32); 256 threads = 4 waves; wave handles 16 q-rows.
// Q: [16384][768] bf16 (pre-scaled). K: [16384][768]. V: [b*12+h][64][512].
// K/V tiles in LDS as [64][64] bf16 with the same granule XOR swizzle.
__global__ __launch_bounds__(256)
void flash(const u16* __restrict__ Q, const u16* __restrict__ K,
           const u16* __restrict__ V, u16* __restrict__ O) {
  __shared__ __align__(16) u16 Ks[2][4096]; // [64 key][64 d] swizzled
  __shared__ __align__(16) u16 Vs[2][4096]; // [64 d][64 key] swizzled
  __shared__ __align__(16) u16 Ps[4][1024]; // per wave [2 k-half][16 r][32 key']
  const int qt = blockIdx.x, h = blockIdx.y, b = blockIdx.z;
  const int tid = threadIdx.x, wave = tid >> 6, lane = tid & 63;
  const int lg = lane >> 4, l15 = lane & 15;
  const int cbx = (lane & 7) ^ ((lane >> 3) & 7);
  bf16x8 qf[2];
  {
    const u16* qp = Q + (size_t)(b * 512 + qt * 64 + wave * 16 + l15) * 768 + h * 64 + lg * 8;
    qf[0] = *(const bf16x8*)qp;
    qf[1] = *(const bf16x8*)(qp + 32);
  }
  f32x4 oacc[4] = {};
  float m_run[4], l_run[4];
#pragma unroll
  for (int r = 0; r < 4; ++r) { m_run[r] = -1e30f; l_run[r] = 0.f; }
  const u16* Kg0 = K + (size_t)(b * 512) * 768 + h * 64;
  const u16* Vg0 = V + (size_t)(b * 12 + h) * 64 * 512;
  u16* pw = Ps[wave];

#define STAGE_KV(bb, kt) do { \
  _Pragma("unroll") for (int j_ = 0; j_ < 2; ++j_) { \
    const int row_ = j_ * 32 + wave * 8 + (lane >> 3); \
    const int go_ = (j_ * 256 + wave * 64 + lane) * 8; \
    gl_lds16(Kg0 + (size_t)((kt) * 64 + row_) * 768 + cbx * 8, &Ks[bb][go_]); \
    gl_lds16(Vg0 + (size_t)row_ * 512 + (kt) * 64 + cbx * 8, &Vs[bb][go_]); \
  } } while (0)

  STAGE_KV(0, 0);
  for (int kt = 0; kt <= qt; ++kt) {
    const int bb = kt & 1;
    if (kt < qt) { STAGE_KV(bb ^ 1, kt + 1); WAITV(4); }
    else         { WAITV(0); }
    BARRIER();
    // QK^T
    f32x4 sc[4] = {};
#pragma unroll
    for (int kc = 0; kc < 2; ++kc) {
#pragma unroll
      for (int t = 0; t < 4; ++t) {
        const int row = t * 16 + l15;
        bf16x8 kf = *(const bf16x8*)&Ks[bb][row * 64 + (((kc * 4 + lg) ^ (l15 & 7)) << 3)];
        sc[t] = MFMA16(qf[kc], kf, sc[t]);
      }
    }
    if (kt == qt) { // diagonal tile: causal mask
#pragma unroll
      for (int t = 0; t < 4; ++t)
#pragma unroll
        for (int r = 0; r < 4; ++r)
          if (t * 16 + l15 > wave * 16 + lg * 4 + r) sc[t][r] = -1e30f;
    }
    // online softmax (row groups of 16 lanes)
    float mx[4], fs[4], rs[4];
#pragma unroll
    for (int r = 0; r < 4; ++r) {
      float m = fmaxf(fmaxf(sc[0][r], sc[1][r]), fmaxf(sc[2][r], sc[3][r]));
      m = fmaxf(m, __shfl_xor(m, 1));
      m = fmaxf(m, __shfl_xor(m, 2));
      m = fmaxf(m, __shfl_xor(m, 4));
      m = fmaxf(m, __shfl_xor(m, 8));
      float mn = fmaxf(m_run[r], m);
      fs[r] = __expf(m_run[r] - mn);
      m_run[r] = mn;
      mx[r] = mn;
      rs[r] = 0.f;
    }
    u16 pb[4][4];
#pragma unroll
    for (int t = 0; t < 4; ++t)
#pragma unroll
      for (int r = 0; r < 4; ++r) {
        float p = __expf(sc[t][r] - mx[r]);
        rs[r] += p;
        pb[t][r] = f2bf(p);
      }
#pragma unroll
    for (int r = 0; r < 4; ++r) {
      rs[r] += __shfl_xor(rs[r], 1);
      rs[r] += __shfl_xor(rs[r], 2);
      rs[r] += __shfl_xor(rs[r], 4);
      rs[r] += __shfl_xor(rs[r], 8);
      l_run[r] = l_run[r] * fs[r] + rs[r];
    }
#pragma unroll
    for (int t = 0; t < 4; ++t)
#pragma unroll
      for (int r = 0; r < 4; ++r)
        oacc[t][r] *= fs[r];
    // stage P (per-wave LDS region)
#pragma unroll
    for (int t = 0; t < 4; ++t)
#pragma unroll
      for (int r = 0; r < 4; ++r)
        pw[(t >> 1) * 512 + (lg * 4 + r) * 32 + (t & 1) * 16 + l15] = pb[t][r];
    // PV
#pragma unroll
    for (int kc = 0; kc < 2; ++kc) {
      bf16x8 pf = *(const bf16x8*)(pw + kc * 512 + l15 * 32 + lg * 8);
#pragma unroll
      for (int t = 0; t < 4; ++t) {
        const int row = t * 16 + l15;
        bf16x8 vf = *(const bf16x8*)&Vs[bb][row * 64 + (((kc * 4 + lg) ^ (l15 & 7)) << 3)];
        oacc[t] = MFMA16(pf, vf, oacc[t]);
      }
    }
    BARRIER(); // exit: all reads of this buffer done before next stage overwrites
  }
#pragma unroll
  for (int r = 0; r < 4; ++r) {
    float inv = 1.f / l_run[r];
#pragma unroll
    for (int t = 0; t < 4; ++t)
      O[(size_t)(b * 512 + qt * 64 + wave * 16 + lg * 4 + r) * 768 + h * 64 + t * 16 + l15] =
          f2bf(oacc[t][r] * inv);
  }
}

extern "C" void kernel_launch(void* const* d_in, const int* in_sizes, int n_in,
                              void* d_out, int out_size, void* d_ws, size_t ws_size,
                              hipStream_t stream) {
  (void)in_sizes; (void)n_in; (void)out_size; (void)ws_size;
  const float* X  = (const float*)d_in[0];
  // d_in[1] = causal mask: exactly triu(-1e9) -> equivalent to hard causal masking; unused.
  const float* Wq = (const float*)d_in[2];
  const float* bq = (const float*)d_in[3];
  const float* Wk = (const float*)d_in[4];
  const float* bk = (const float*)d_in[5];
  const float* Wv = (const float*)d_in[6];
  const float* bv = (const float*)d_in[7];
  const float* Wo = (const float*)d_in[8];
  const float* bo = (const float*)d_in[9];
  float* out = (float*)d_out;

  const size_t NME = (size_t)16384 * 768;
  u16* Xb  = (u16*)d_ws;        // bf16 X, later reused as attention output
  u16* Qs  = Xb + NME;
  u16* Kb  = Qs + NME;
  u16* Vt  = Kb + NME;          // [b*12+h][64][512]
  u16* WT  = Vt + NME;          // [2304][768]  (WqT | WkT | WvT)
  u16* WoT = WT + (size_t)2304 * 768;
  u16* Ao  = Xb;

  convert_x<<<6144, 256, 0, stream>>>(X, Xb);
  dim3 tb(32, 8);
  transpose_w<<<dim3(24, 24), tb, 0, stream>>>(Wq, WT);
  transpose_w<<<dim3(24, 24), tb, 0, stream>>>(Wk, WT + (size_t)768 * 768);
  transpose_w<<<dim3(24, 24), tb, 0, stream>>>(Wv, WT + (size_t)2 * 768 * 768);
  transpose_w<<<dim3(24, 24), tb, 0, stream>>>(Wo, WoT);
  gemmP<0><<<dim3(128, 9), 512, 0, stream>>>(Xb, WT, bq, bk, bv, Qs, Kb, Vt, nullptr);
  flash<<<dim3(8, 12, 32), 256, 0, stream>>>(Qs, Kb, Vt, Ao);
  gemmP<1><<<dim3(128, 3), 512, 0, stream>>>(Ao, WoT, bo, nullptr, nullptr,
                                             nullptr, nullptr, nullptr, out);
}

// Round 4
// 207.201 us; speedup vs baseline: 2.9531x; 1.1044x over previous
//
#include <hip/hip_runtime.h>
#include <hip/hip_bf16.h>

typedef __attribute__((ext_vector_type(8))) short bf16x8;
typedef __attribute__((ext_vector_type(4))) float f32x4;
typedef unsigned short u16;
typedef unsigned int u32;

#define MFMA16(a,b,c) __builtin_amdgcn_mfma_f32_16x16x32_bf16((a),(b),(c),0,0,0)
#define FENCE() asm volatile("" ::: "memory")
#define BARRIER() do { FENCE(); __builtin_amdgcn_s_barrier(); FENCE(); } while (0)
#define WAITV(N) asm volatile("s_waitcnt vmcnt(" #N ")" ::: "memory")

__device__ __forceinline__ u16 f2bf(float f) {
  union { float f; u32 u; } c; c.f = f;
  u32 u = c.u;
  return (u16)((u + 0x7FFFu + ((u >> 16) & 1u)) >> 16);
}

// packed pair: low u16 = lo, high u16 = hi (RNE via v_cvt_pk_bf16_f32)
__device__ __forceinline__ u32 pk2(float lo, float hi) {
  __hip_bfloat162 h2 = __float22bfloat162_rn(float2{lo, hi});
  union { __hip_bfloat162 h; u32 u; } c; c.h = h2; return c.u;
}

__device__ __forceinline__ void gl_lds16(const u16* g, u16* l) {
  __builtin_amdgcn_global_load_lds((const __attribute__((address_space(1))) void*)g,
                                   (__attribute__((address_space(3))) void*)l, 16, 0, 0);
}

// ---------------- prep: X fp32->bf16 (blocks 0..6143) + 4x W transpose ----
__global__ __launch_bounds__(256) void prep(const float* __restrict__ X,
                                            u16* __restrict__ Xb,
                                            const float* __restrict__ Wq,
                                            const float* __restrict__ Wk,
                                            const float* __restrict__ Wv,
                                            const float* __restrict__ Wo,
                                            u16* __restrict__ WT) {
  const int blk = blockIdx.x, tid = threadIdx.x;
  if (blk < 6144) {
    int i = (blk * 256 + tid) * 8;
    const float4* p = (const float4*)(X + i);
    float4 a = p[0], b = p[1];
    union { u16 h[8]; uint4 v; } o;
    o.h[0] = f2bf(a.x); o.h[1] = f2bf(a.y); o.h[2] = f2bf(a.z); o.h[3] = f2bf(a.w);
    o.h[4] = f2bf(b.x); o.h[5] = f2bf(b.y); o.h[6] = f2bf(b.z); o.h[7] = f2bf(b.w);
    *(uint4*)(Xb + i) = o.v;
  } else {
    __shared__ float t[32][33];
    const int q = blk - 6144;
    const int w = q / 576, p = q % 576;
    const float* W = (w == 0) ? Wq : (w == 1) ? Wk : (w == 2) ? Wv : Wo;
    u16* D = WT + (size_t)w * 768 * 768;
    const int n0 = (p % 24) * 32, k0 = (p / 24) * 32;
    const int tx = tid & 31, ty = tid >> 5;
#pragma unroll
    for (int i = 0; i < 4; ++i)
      t[ty + i * 8][tx] = W[(size_t)(k0 + ty + i * 8) * 768 + n0 + tx];
    __syncthreads();
#pragma unroll
    for (int i = 0; i < 4; ++i)
      D[(size_t)(n0 + ty + i * 8) * 768 + k0 + tx] = f2bf(t[tx][ty + i * 8]);
  }
}

// ---------------- GEMM 128x256, BK=64, 8 waves, 3-buffer 2-deep pipeline ----
// C[m][n] = sum_k A[m][k] * BT[n][k] (+bias).  1-D grid, chunked XCD swizzle.
// MODE 0: QKV (N=2304): Q bf16 (scaled 1/8), K bf16, V bf16 transposed per (b,h)
// MODE 1: out-proj (N=768): fp32 + bias

#define STA(bu, t) do { _Pragma("unroll") for (int s_ = 0; s_ < 2; ++s_) { \
    const int r_ = s_ * 64 + srow; \
    gl_lds16(A + (size_t)(M0 + r_) * 768 + (t) * 64 + ((sg ^ (r_ & 7)) << 3), \
             &As[bu][r_ * 64 + sg * 8]); } } while (0)
#define STB(bu, t) do { _Pragma("unroll") for (int s_ = 0; s_ < 4; ++s_) { \
    const int r_ = s_ * 64 + srow; \
    gl_lds16(BT + (size_t)(N0 + r_) * 768 + (t) * 64 + ((sg ^ (r_ & 7)) << 3), \
             &Bs[bu][r_ * 64 + sg * 8]); } } while (0)

template <int MODE>
__global__ __launch_bounds__(512, 2)
void gemmP(const u16* __restrict__ A, const u16* __restrict__ BT,
           const float* __restrict__ b0, const float* __restrict__ b1,
           const float* __restrict__ b2,
           u16* __restrict__ oQ, u16* __restrict__ oK, u16* __restrict__ oV,
           float* __restrict__ oF, int chunk) {
  constexpr int NT = 12; // K = 768 = 12 * 64
  __shared__ __align__(16) u16 As[3][128 * 64];
  __shared__ __align__(16) u16 Bs[3][256 * 64];
  const int tid = threadIdx.x;
  const int wave = tid >> 6, lane = tid & 63;
  const int lg = lane >> 4, l15 = lane & 15;
  const int wr = wave >> 2, wc = wave & 3;
  const int bi = blockIdx.x;
  const int tt = (bi & 7) * chunk + (bi >> 3); // bijective XCD chunking
  const int M0 = (tt & 127) * 128, N0 = (tt >> 7) * 256;
  const int srow = tid >> 3, sg = tid & 7;

  f32x4 acc[4][4] = {};

  STA(0, 0); STB(0, 0);
  STA(1, 1); STB(1, 1);

#pragma unroll
  for (int t = 0; t < NT; ++t) {
    if (t < NT - 1) { WAITV(6); } else { WAITV(0); }
    BARRIER(); // buf[t%3] ready; buf[(t+2)%3] == buf[(t-1)%3] free
    if (t + 2 < NT) {
      STA((t + 2) % 3, t + 2);
      STB((t + 2) % 3, t + 2);
    }
    const int bb = t % 3;
    __builtin_amdgcn_s_setprio(1);
    bf16x8 bfr[4][2];
#pragma unroll
    for (int nt = 0; nt < 4; ++nt)
#pragma unroll
      for (int kh = 0; kh < 2; ++kh) {
        const int row = wc * 64 + nt * 16 + l15;
        bfr[nt][kh] = *(const bf16x8*)&Bs[bb][row * 64 + (((kh * 4 + lg) ^ (row & 7)) << 3)];
      }
#pragma unroll
    for (int mt = 0; mt < 4; ++mt) {
      bf16x8 af[2];
#pragma unroll
      for (int kh = 0; kh < 2; ++kh) {
        const int row = wr * 64 + mt * 16 + l15;
        af[kh] = *(const bf16x8*)&As[bb][row * 64 + (((kh * 4 + lg) ^ (row & 7)) << 3)];
      }
#pragma unroll
      for (int nt = 0; nt < 4; ++nt)
#pragma unroll
        for (int kh = 0; kh < 2; ++kh)
          acc[mt][nt] = MFMA16(af[kh], bfr[nt][kh], acc[mt][nt]);
    }
    __builtin_amdgcn_s_setprio(0);
  }

#pragma unroll
  for (int mt = 0; mt < 4; ++mt) {
    const int r0 = M0 + wr * 64 + mt * 16 + lg * 4;
#pragma unroll
    for (int nt = 0; nt < 4; ++nt) {
      const int ng = N0 + wc * 64 + nt * 16 + l15;
      f32x4 v = acc[mt][nt];
      if (MODE == 1) {
        const float bb = b0[ng];
#pragma unroll
        for (int r = 0; r < 4; ++r)
          oF[(size_t)(r0 + r) * 768 + ng] = v[r] + bb;
      } else {
        const int mat = ng / 768;
        const int col = ng - mat * 768;
        const float bb = (mat == 0 ? b0 : (mat == 1 ? b1 : b2))[col];
        if (mat == 0) {
#pragma unroll
          for (int r = 0; r < 4; ++r)
            oQ[(size_t)(r0 + r) * 768 + col] = f2bf((v[r] + bb) * 0.125f);
        } else if (mat == 1) {
#pragma unroll
          for (int r = 0; r < 4; ++r)
            oK[(size_t)(r0 + r) * 768 + col] = f2bf(v[r] + bb);
        } else {
          const int hh = col >> 6, dd = col & 63;
#pragma unroll
          for (int r = 0; r < 4; ++r) {
            const int rr = r0 + r;
            const int bbx = rr >> 9, ss = rr & 511;
            oV[((size_t)(bbx * 12 + hh) * 64 + dd) * 512 + ss] = f2bf(v[r] + bb);
          }
        }
      }
    }
  }
}

// ---------------- causal flash attention, swapped-operand, 8 waves ----------
// grid: 1536 1-D; id -> qt = id/384 (q-tile of 128 rows), hb = id%384
// (h = hb%12, b = hb/12).  All qt of one (b,h) land on one XCD (id%8 = hb%8).
// Swapped QK^T: sc = mfma(K,Q) -> lane l15 owns q-row (wave*16+l15); regs hold
// keys t*16+lg*4+r.  Swapped PV: o = mfma(V^T,P) -> lane holds q-col, d rows.
// K/V: 3 LDS buffers, 1 barrier/tile, vmcnt(2) counted prefetch.
#define STG(bu, kt) do { \
    gl_lds16(Kg0 + (size_t)((kt) * 64 + srow) * 768 + sgr * 8, \
             &Ks[bu][srow * 64 + (tid & 7) * 8]); \
    gl_lds16(Vg0 + (size_t)srow * 512 + (kt) * 64 + sgr * 8, \
             &Vs[bu][srow * 64 + (tid & 7) * 8]); \
  } while (0)

__global__ __launch_bounds__(512, 2)
void flash(const u16* __restrict__ Q, const u16* __restrict__ K,
           const u16* __restrict__ V, u16* __restrict__ O) {
  __shared__ __align__(16) u16 Ks[3][4096]; // [64 key][64 d] swizzled granules
  __shared__ __align__(16) u16 Vs[3][4096]; // [64 d][64 key] swizzled granules
  __shared__ __align__(16) u32 Ps[8][16 * 36]; // per wave: [16 q][32+4 pad words]
  const int id = blockIdx.x;
  const int qt = id / 384, hb = id % 384;
  const int h = hb % 12, b = hb / 12;
  const int tid = threadIdx.x, wave = tid >> 6, lane = tid & 63;
  const int lg = lane >> 4, l15 = lane & 15;
  const int NT = 2 * qt + 2;
  const int srow = tid >> 3, sgr = (tid & 7) ^ (srow & 7);
  const int qbase = qt * 128 + wave * 16; // wave's first q row (within head)

  bf16x8 qf[2];
  {
    const u16* qp = Q + (size_t)(b * 512 + qbase + l15) * 768 + h * 64 + lg * 8;
    qf[0] = *(const bf16x8*)qp;
    qf[1] = *(const bf16x8*)(qp + 32);
  }
  f32x4 oacc[4] = {};
  float m_run = -1e30f, l_run = 0.f;
  const u16* Kg0 = K + (size_t)(b * 512) * 768 + h * 64;
  const u16* Vg0 = V + (size_t)(b * 12 + h) * 64 * 512;
  u32* pw = Ps[wave];

  STG(0, 0);
  STG(1, 1);
  for (int kt = 0; kt < NT; ++kt) {
    if (kt < NT - 1) { WAITV(2); } else { WAITV(0); }
    BARRIER(); // buf kt%3 ready; buf (kt+2)%3 == (kt-1)%3 free
    if (kt + 2 < NT) STG((kt + 2) % 3, kt + 2);
    const int bu = kt % 3;
    if (kt * 64 <= qbase + 15) { // wave has at least one unmasked key
      // ---- QK^T (swapped): rows=keys, cols=q ----
      f32x4 sc[4] = {};
#pragma unroll
      for (int kc = 0; kc < 2; ++kc)
#pragma unroll
        for (int t = 0; t < 4; ++t) {
          const int row = t * 16 + l15;
          bf16x8 kf = *(const bf16x8*)&Ks[bu][row * 64 + (((kc * 4 + lg) ^ (l15 & 7)) << 3)];
          sc[t] = MFMA16(kf, qf[kc], sc[t]);
        }
      if (kt * 64 + 63 > qbase) { // boundary tile: causal mask (key > q)
#pragma unroll
        for (int t = 0; t < 4; ++t)
#pragma unroll
          for (int r = 0; r < 4; ++r)
            if (kt * 64 + t * 16 + lg * 4 + r > qbase + l15) sc[t][r] = -1e30f;
      }
      // ---- online softmax: q-row is lane-local up to the 4 lg groups ----
      float pm = sc[0][0];
#pragma unroll
      for (int t = 0; t < 4; ++t)
#pragma unroll
        for (int r = 0; r < 4; ++r) pm = fmaxf(pm, sc[t][r]);
      pm = fmaxf(pm, __shfl_xor(pm, 16));
      pm = fmaxf(pm, __shfl_xor(pm, 32));
      if (__any(pm > m_run + 8.f)) { // defer-max: rescale only on real growth
        const float mn = fmaxf(m_run, pm);
        const float fs = __expf(m_run - mn);
        m_run = mn;
        l_run *= fs;
#pragma unroll
        for (int t = 0; t < 4; ++t)
#pragma unroll
          for (int r = 0; r < 4; ++r) oacc[t][r] *= fs;
      }
      float rs = 0.f;
#pragma unroll
      for (int t = 0; t < 4; ++t) {
        float p0 = __expf(sc[t][0] - m_run), p1 = __expf(sc[t][1] - m_run);
        float p2 = __expf(sc[t][2] - m_run), p3 = __expf(sc[t][3] - m_run);
        rs += (p0 + p1) + (p2 + p3);
        pw[l15 * 36 + t * 8 + lg * 2 + 0] = pk2(p0, p1);
        pw[l15 * 36 + t * 8 + lg * 2 + 1] = pk2(p2, p3);
      }
      rs += __shfl_xor(rs, 16);
      rs += __shfl_xor(rs, 32);
      l_run += rs;
      // ---- PV (swapped): A=V^T rows=d, B=P cols=q ----
#pragma unroll
      for (int kc = 0; kc < 2; ++kc) {
        bf16x8 pf = *(const bf16x8*)&pw[l15 * 36 + kc * 16 + lg * 4];
#pragma unroll
        for (int t = 0; t < 4; ++t) {
          const int row = t * 16 + l15;
          bf16x8 vf = *(const bf16x8*)&Vs[bu][row * 64 + (((kc * 4 + lg) ^ (l15 & 7)) << 3)];
          oacc[t] = MFMA16(vf, pf, oacc[t]);
        }
      }
    }
  }
  const float inv = 1.f / l_run;
  u16* op = O + (size_t)(b * 512 + qbase + l15) * 768 + h * 64;
#pragma unroll
  for (int t = 0; t < 4; ++t) {
    uint2 w;
    w.x = pk2(oacc[t][0] * inv, oacc[t][1] * inv);
    w.y = pk2(oacc[t][2] * inv, oacc[t][3] * inv);
    *(uint2*)(op + t * 16 + lg * 4) = w;
  }
}

extern "C" void kernel_launch(void* const* d_in, const int* in_sizes, int n_in,
                              void* d_out, int out_size, void* d_ws, size_t ws_size,
                              hipStream_t stream) {
  (void)in_sizes; (void)n_in; (void)out_size; (void)ws_size;
  const float* X  = (const float*)d_in[0];
  // d_in[1] = causal mask: exactly triu(-1e9) -> equivalent to hard causal masking; unused.
  const float* Wq = (const float*)d_in[2];
  const float* bq = (const float*)d_in[3];
  const float* Wk = (const float*)d_in[4];
  const float* bk = (const float*)d_in[5];
  const float* Wv = (const float*)d_in[6];
  const float* bv = (const float*)d_in[7];
  const float* Wo = (const float*)d_in[8];
  const float* bo = (const float*)d_in[9];
  float* out = (float*)d_out;

  const size_t NME = (size_t)16384 * 768;
  u16* Xb  = (u16*)d_ws;        // bf16 X, later reused as attention output
  u16* Qs  = Xb + NME;
  u16* Kb  = Qs + NME;
  u16* Vt  = Kb + NME;          // [b*12+h][64][512]
  u16* WT  = Vt + NME;          // [3072][768]  (WqT | WkT | WvT | WoT)
  u16* WoT = WT + (size_t)2304 * 768;
  u16* Ao  = Xb;

  prep<<<8448, 256, 0, stream>>>(X, Xb, Wq, Wk, Wv, Wo, WT);
  gemmP<0><<<1152, 512, 0, stream>>>(Xb, WT, bq, bk, bv, Qs, Kb, Vt, nullptr, 144);
  flash<<<1536, 512, 0, stream>>>(Qs, Kb, Vt, Ao);
  gemmP<1><<<384, 512, 0, stream>>>(Ao, WoT, bo, nullptr, nullptr,
                                    nullptr, nullptr, nullptr, out, 48);
}

// Round 5
// 174.804 us; speedup vs baseline: 3.5004x; 1.1853x over previous
//
#include <hip/hip_runtime.h>
#include <hip/hip_bf16.h>

typedef __attribute__((ext_vector_type(8))) short bf16x8;
typedef __attribute__((ext_vector_type(4))) float f32x4;
typedef unsigned short u16;
typedef unsigned int u32;

#define MFMA16(a,b,c) __builtin_amdgcn_mfma_f32_16x16x32_bf16((a),(b),(c),0,0,0)
#define FENCE() asm volatile("" ::: "memory")
#define BARRIER() do { FENCE(); __builtin_amdgcn_s_barrier(); FENCE(); } while (0)
#define WAITV(N) asm volatile("s_waitcnt vmcnt(" #N ")" ::: "memory")

__device__ __forceinline__ u16 f2bf(float f) {
  union { float f; u32 u; } c; c.f = f;
  u32 u = c.u;
  return (u16)((u + 0x7FFFu + ((u >> 16) & 1u)) >> 16);
}

// packed pair: low u16 = lo, high u16 = hi (RNE via v_cvt_pk_bf16_f32)
__device__ __forceinline__ u32 pk2(float lo, float hi) {
  __hip_bfloat162 h2 = __float22bfloat162_rn(float2{lo, hi});
  union { __hip_bfloat162 h; u32 u; } c; c.h = h2; return c.u;
}

__device__ __forceinline__ void gl_lds16(const u16* g, u16* l) {
  __builtin_amdgcn_global_load_lds((const __attribute__((address_space(1))) void*)g,
                                   (__attribute__((address_space(3))) void*)l, 16, 0, 0);
}

// ---------------- prep: X fp32->bf16 (blocks 0..6143) + 4x W transpose ----
__global__ __launch_bounds__(256) void prep(const float* __restrict__ X,
                                            u16* __restrict__ Xb,
                                            const float* __restrict__ Wq,
                                            const float* __restrict__ Wk,
                                            const float* __restrict__ Wv,
                                            const float* __restrict__ Wo,
                                            u16* __restrict__ WT) {
  const int blk = blockIdx.x, tid = threadIdx.x;
  if (blk < 6144) {
    int i = (blk * 256 + tid) * 8;
    const float4* p = (const float4*)(X + i);
    float4 a = p[0], b = p[1];
    union { u16 h[8]; uint4 v; } o;
    o.h[0] = f2bf(a.x); o.h[1] = f2bf(a.y); o.h[2] = f2bf(a.z); o.h[3] = f2bf(a.w);
    o.h[4] = f2bf(b.x); o.h[5] = f2bf(b.y); o.h[6] = f2bf(b.z); o.h[7] = f2bf(b.w);
    *(uint4*)(Xb + i) = o.v;
  } else {
    __shared__ float t[32][33];
    const int q = blk - 6144;
    const int w = q / 576, p = q % 576;
    const float* W = (w == 0) ? Wq : (w == 1) ? Wk : (w == 2) ? Wv : Wo;
    u16* D = WT + (size_t)w * 768 * 768;
    const int n0 = (p % 24) * 32, k0 = (p / 24) * 32;
    const int tx = tid & 31, ty = tid >> 5;
#pragma unroll
    for (int i = 0; i < 4; ++i)
      t[ty + i * 8][tx] = W[(size_t)(k0 + ty + i * 8) * 768 + n0 + tx];
    __syncthreads();
#pragma unroll
    for (int i = 0; i < 4; ++i)
      D[(size_t)(n0 + ty + i * 8) * 768 + k0 + tx] = f2bf(t[tx][ty + i * 8]);
  }
}

// ---------------- GEMM 128x256, BK=64, 8 waves, 3-buffer 2-deep pipeline ----
// C[m][n] = sum_k A[m][k] * BT[n][k] (+bias).
// Grid mapping (T1, corrected): each XCD (bi&7) owns a 16-M-tile band;
// within the band, N-fastest -> per-XCD working set = few A-tiles (0.8 MB)
// + all B panels (<=3.5 MB) ~ fits 4 MB L2. Round-4's M-fastest chunk
// streamed ALL of A (25 MB) per XCD -> 119 MB L2 fill, 2x slowdown.
// MODE 0: QKV (N=2304): Q bf16 (scaled 1/8), K bf16, V bf16 transposed per (b,h)
// MODE 1: out-proj (N=768): fp32 + bias

#define STA(bu, t) do { _Pragma("unroll") for (int s_ = 0; s_ < 2; ++s_) { \
    const int r_ = s_ * 64 + srow; \
    gl_lds16(A + (size_t)(M0 + r_) * 768 + (t) * 64 + ((sg ^ (r_ & 7)) << 3), \
             &As[bu][r_ * 64 + sg * 8]); } } while (0)
#define STB(bu, t) do { _Pragma("unroll") for (int s_ = 0; s_ < 4; ++s_) { \
    const int r_ = s_ * 64 + srow; \
    gl_lds16(BT + (size_t)(N0 + r_) * 768 + (t) * 64 + ((sg ^ (r_ & 7)) << 3), \
             &Bs[bu][r_ * 64 + sg * 8]); } } while (0)

template <int MODE>
__global__ __launch_bounds__(512, 2)
void gemmP(const u16* __restrict__ A, const u16* __restrict__ BT,
           const float* __restrict__ b0, const float* __restrict__ b1,
           const float* __restrict__ b2,
           u16* __restrict__ oQ, u16* __restrict__ oK, u16* __restrict__ oV,
           float* __restrict__ oF, int nN) {
  constexpr int NT = 12; // K = 768 = 12 * 64
  __shared__ __align__(16) u16 As[3][128 * 64];
  __shared__ __align__(16) u16 Bs[3][256 * 64];
  const int tid = threadIdx.x;
  const int wave = tid >> 6, lane = tid & 63;
  const int lg = lane >> 4, l15 = lane & 15;
  const int wr = wave >> 2, wc = wave & 3;
  const int bi = blockIdx.x;
  const int j = bi >> 3;
  const int M0 = ((bi & 7) * 16 + j / nN) * 128; // XCD-band of 16 M-tiles
  const int N0 = (j % nN) * 256;                 // N-fastest within band
  const int srow = tid >> 3, sg = tid & 7;

  f32x4 acc[4][4] = {};

  STA(0, 0); STB(0, 0);
  STA(1, 1); STB(1, 1);

#pragma unroll
  for (int t = 0; t < NT; ++t) {
    if (t < NT - 1) { WAITV(6); } else { WAITV(0); }
    BARRIER(); // buf[t%3] ready; buf[(t+2)%3] == buf[(t-1)%3] free
    if (t + 2 < NT) {
      STA((t + 2) % 3, t + 2);
      STB((t + 2) % 3, t + 2);
    }
    const int bb = t % 3;
    __builtin_amdgcn_s_setprio(1);
    bf16x8 bfr[4][2];
#pragma unroll
    for (int nt = 0; nt < 4; ++nt)
#pragma unroll
      for (int kh = 0; kh < 2; ++kh) {
        const int row = wc * 64 + nt * 16 + l15;
        bfr[nt][kh] = *(const bf16x8*)&Bs[bb][row * 64 + (((kh * 4 + lg) ^ (row & 7)) << 3)];
      }
#pragma unroll
    for (int mt = 0; mt < 4; ++mt) {
      bf16x8 af[2];
#pragma unroll
      for (int kh = 0; kh < 2; ++kh) {
        const int row = wr * 64 + mt * 16 + l15;
        af[kh] = *(const bf16x8*)&As[bb][row * 64 + (((kh * 4 + lg) ^ (row & 7)) << 3)];
      }
#pragma unroll
      for (int nt = 0; nt < 4; ++nt)
#pragma unroll
        for (int kh = 0; kh < 2; ++kh)
          acc[mt][nt] = MFMA16(af[kh], bfr[nt][kh], acc[mt][nt]);
    }
    __builtin_amdgcn_s_setprio(0);
  }

#pragma unroll
  for (int mt = 0; mt < 4; ++mt) {
    const int r0 = M0 + wr * 64 + mt * 16 + lg * 4;
#pragma unroll
    for (int nt = 0; nt < 4; ++nt) {
      const int ng = N0 + wc * 64 + nt * 16 + l15;
      f32x4 v = acc[mt][nt];
      if (MODE == 1) {
        const float bb = b0[ng];
#pragma unroll
        for (int r = 0; r < 4; ++r)
          oF[(size_t)(r0 + r) * 768 + ng] = v[r] + bb;
      } else {
        const int mat = ng / 768;
        const int col = ng - mat * 768;
        const float bb = (mat == 0 ? b0 : (mat == 1 ? b1 : b2))[col];
        if (mat == 0) {
#pragma unroll
          for (int r = 0; r < 4; ++r)
            oQ[(size_t)(r0 + r) * 768 + col] = f2bf((v[r] + bb) * 0.125f);
        } else if (mat == 1) {
#pragma unroll
          for (int r = 0; r < 4; ++r)
            oK[(size_t)(r0 + r) * 768 + col] = f2bf(v[r] + bb);
        } else {
          const int hh = col >> 6, dd = col & 63;
#pragma unroll
          for (int r = 0; r < 4; ++r) {
            const int rr = r0 + r;
            const int bbx = rr >> 9, ss = rr & 511;
            oV[((size_t)(bbx * 12 + hh) * 64 + dd) * 512 + ss] = f2bf(v[r] + bb);
          }
        }
      }
    }
  }
}

// ---------------- causal flash attention, swapped-operand, 8 waves ----------
// grid: 1536 1-D; id -> qt = id/384 (q-tile of 128 rows), hb = id%384
// (h = hb%12, b = hb/12).  All qt of one (b,h) land on one XCD (id%8 = hb%8).
// Swapped QK^T: sc = mfma(K,Q) -> lane l15 owns q-row (wave*16+l15); regs hold
// keys t*16+lg*4+r.  Swapped PV: o = mfma(V^T,P) -> lane holds q-col, d rows.
// K/V: 3 LDS buffers, 1 barrier/tile, vmcnt(2) counted prefetch.
#define STG(bu, kt) do { \
    gl_lds16(Kg0 + (size_t)((kt) * 64 + srow) * 768 + sgr * 8, \
             &Ks[bu][srow * 64 + (tid & 7) * 8]); \
    gl_lds16(Vg0 + (size_t)srow * 512 + (kt) * 64 + sgr * 8, \
             &Vs[bu][srow * 64 + (tid & 7) * 8]); \
  } while (0)

__global__ __launch_bounds__(512, 2)
void flash(const u16* __restrict__ Q, const u16* __restrict__ K,
           const u16* __restrict__ V, u16* __restrict__ O) {
  __shared__ __align__(16) u16 Ks[3][4096]; // [64 key][64 d] swizzled granules
  __shared__ __align__(16) u16 Vs[3][4096]; // [64 d][64 key] swizzled granules
  __shared__ __align__(16) u32 Ps[8][16 * 36]; // per wave: [16 q][32+4 pad words]
  const int id = blockIdx.x;
  const int qt = id / 384, hb = id % 384;
  const int h = hb % 12, b = hb / 12;
  const int tid = threadIdx.x, wave = tid >> 6, lane = tid & 63;
  const int lg = lane >> 4, l15 = lane & 15;
  const int NT = 2 * qt + 2;
  const int srow = tid >> 3, sgr = (tid & 7) ^ (srow & 7);
  const int qbase = qt * 128 + wave * 16; // wave's first q row (within head)

  bf16x8 qf[2];
  {
    const u16* qp = Q + (size_t)(b * 512 + qbase + l15) * 768 + h * 64 + lg * 8;
    qf[0] = *(const bf16x8*)qp;
    qf[1] = *(const bf16x8*)(qp + 32);
  }
  f32x4 oacc[4] = {};
  float m_run = -1e30f, l_run = 0.f;
  const u16* Kg0 = K + (size_t)(b * 512) * 768 + h * 64;
  const u16* Vg0 = V + (size_t)(b * 12 + h) * 64 * 512;
  u32* pw = Ps[wave];

  STG(0, 0);
  STG(1, 1);
  for (int kt = 0; kt < NT; ++kt) {
    if (kt < NT - 1) { WAITV(2); } else { WAITV(0); }
    BARRIER(); // buf kt%3 ready; buf (kt+2)%3 == (kt-1)%3 free
    if (kt + 2 < NT) STG((kt + 2) % 3, kt + 2);
    const int bu = kt % 3;
    if (kt * 64 <= qbase + 15) { // wave has at least one unmasked key
      // ---- QK^T (swapped): rows=keys, cols=q ----
      f32x4 sc[4] = {};
#pragma unroll
      for (int kc = 0; kc < 2; ++kc)
#pragma unroll
        for (int t = 0; t < 4; ++t) {
          const int row = t * 16 + l15;
          bf16x8 kf = *(const bf16x8*)&Ks[bu][row * 64 + (((kc * 4 + lg) ^ (l15 & 7)) << 3)];
          sc[t] = MFMA16(kf, qf[kc], sc[t]);
        }
      if (kt * 64 + 63 > qbase) { // boundary tile: causal mask (key > q)
#pragma unroll
        for (int t = 0; t < 4; ++t)
#pragma unroll
          for (int r = 0; r < 4; ++r)
            if (kt * 64 + t * 16 + lg * 4 + r > qbase + l15) sc[t][r] = -1e30f;
      }
      // ---- online softmax: q-row is lane-local up to the 4 lg groups ----
      float pm = sc[0][0];
#pragma unroll
      for (int t = 0; t < 4; ++t)
#pragma unroll
        for (int r = 0; r < 4; ++r) pm = fmaxf(pm, sc[t][r]);
      pm = fmaxf(pm, __shfl_xor(pm, 16));
      pm = fmaxf(pm, __shfl_xor(pm, 32));
      if (__any(pm > m_run + 8.f)) { // defer-max: rescale only on real growth
        const float mn = fmaxf(m_run, pm);
        const float fs = __expf(m_run - mn);
        m_run = mn;
        l_run *= fs;
#pragma unroll
        for (int t = 0; t < 4; ++t)
#pragma unroll
          for (int r = 0; r < 4; ++r) oacc[t][r] *= fs;
      }
      float rs = 0.f;
#pragma unroll
      for (int t = 0; t < 4; ++t) {
        float p0 = __expf(sc[t][0] - m_run), p1 = __expf(sc[t][1] - m_run);
        float p2 = __expf(sc[t][2] - m_run), p3 = __expf(sc[t][3] - m_run);
        rs += (p0 + p1) + (p2 + p3);
        pw[l15 * 36 + t * 8 + lg * 2 + 0] = pk2(p0, p1);
        pw[l15 * 36 + t * 8 + lg * 2 + 1] = pk2(p2, p3);
      }
      rs += __shfl_xor(rs, 16);
      rs += __shfl_xor(rs, 32);
      l_run += rs;
      // ---- PV (swapped): A=V^T rows=d, B=P cols=q ----
#pragma unroll
      for (int kc = 0; kc < 2; ++kc) {
        bf16x8 pf = *(const bf16x8*)&pw[l15 * 36 + kc * 16 + lg * 4];
#pragma unroll
        for (int t = 0; t < 4; ++t) {
          const int row = t * 16 + l15;
          bf16x8 vf = *(const bf16x8*)&Vs[bu][row * 64 + (((kc * 4 + lg) ^ (l15 & 7)) << 3)];
          oacc[t] = MFMA16(vf, pf, oacc[t]);
        }
      }
    }
  }
  const float inv = 1.f / l_run;
  u16* op = O + (size_t)(b * 512 + qbase + l15) * 768 + h * 64;
#pragma unroll
  for (int t = 0; t < 4; ++t) {
    uint2 w;
    w.x = pk2(oacc[t][0] * inv, oacc[t][1] * inv);
    w.y = pk2(oacc[t][2] * inv, oacc[t][3] * inv);
    *(uint2*)(op + t * 16 + lg * 4) = w;
  }
}

extern "C" void kernel_launch(void* const* d_in, const int* in_sizes, int n_in,
                              void* d_out, int out_size, void* d_ws, size_t ws_size,
                              hipStream_t stream) {
  (void)in_sizes; (void)n_in; (void)out_size; (void)ws_size;
  const float* X  = (const float*)d_in[0];
  // d_in[1] = causal mask: exactly triu(-1e9) -> equivalent to hard causal masking; unused.
  const float* Wq = (const float*)d_in[2];
  const float* bq = (const float*)d_in[3];
  const float* Wk = (const float*)d_in[4];
  const float* bk = (const float*)d_in[5];
  const float* Wv = (const float*)d_in[6];
  const float* bv = (const float*)d_in[7];
  const float* Wo = (const float*)d_in[8];
  const float* bo = (const float*)d_in[9];
  float* out = (float*)d_out;

  const size_t NME = (size_t)16384 * 768;
  u16* Xb  = (u16*)d_ws;        // bf16 X, later reused as attention output
  u16* Qs  = Xb + NME;
  u16* Kb  = Qs + NME;
  u16* Vt  = Kb + NME;          // [b*12+h][64][512]
  u16* WT  = Vt + NME;          // [3072][768]  (WqT | WkT | WvT | WoT)
  u16* WoT = WT + (size_t)2304 * 768;
  u16* Ao  = Xb;

  prep<<<8448, 256, 0, stream>>>(X, Xb, Wq, Wk, Wv, Wo, WT);
  gemmP<0><<<1152, 512, 0, stream>>>(Xb, WT, bq, bk, bv, Qs, Kb, Vt, nullptr, 9);
  flash<<<1536, 512, 0, stream>>>(Qs, Kb, Vt, Ao);
  gemmP<1><<<384, 512, 0, stream>>>(Ao, WoT, bo, nullptr, nullptr,
                                    nullptr, nullptr, nullptr, out, 3);
}

// Round 6
// 148.215 us; speedup vs baseline: 4.1284x; 1.1794x over previous
//
#include <hip/hip_runtime.h>
#include <hip/hip_bf16.h>

typedef __attribute__((ext_vector_type(8))) short bf16x8;
typedef __attribute__((ext_vector_type(4))) float f32x4;
typedef unsigned short u16;
typedef unsigned int u32;

#define MFMA16(a,b,c) __builtin_amdgcn_mfma_f32_16x16x32_bf16((a),(b),(c),0,0,0)
#define FENCE() asm volatile("" ::: "memory")
#define BARRIER() do { FENCE(); __builtin_amdgcn_s_barrier(); FENCE(); } while (0)
#define WAITV(N) asm volatile("s_waitcnt vmcnt(" #N ")" ::: "memory")

__device__ __forceinline__ u16 f2bf(float f) {
  union { float f; u32 u; } c; c.f = f;
  u32 u = c.u;
  return (u16)((u + 0x7FFFu + ((u >> 16) & 1u)) >> 16);
}

// packed pair: low u16 = lo, high u16 = hi (RNE via v_cvt_pk_bf16_f32)
__device__ __forceinline__ u32 pk2(float lo, float hi) {
  __hip_bfloat162 h2 = __float22bfloat162_rn(float2{lo, hi});
  union { __hip_bfloat162 h; u32 u; } c; c.h = h2; return c.u;
}

__device__ __forceinline__ void gl_lds16(const u16* g, u16* l) {
  __builtin_amdgcn_global_load_lds((const __attribute__((address_space(1))) void*)g,
                                   (__attribute__((address_space(3))) void*)l, 16, 0, 0);
}

// ---------------- prep: X fp32->bf16 (blocks 0..6143) + 4x W transpose ----
__global__ __launch_bounds__(256) void prep(const float* __restrict__ X,
                                            u16* __restrict__ Xb,
                                            const float* __restrict__ Wq,
                                            const float* __restrict__ Wk,
                                            const float* __restrict__ Wv,
                                            const float* __restrict__ Wo,
                                            u16* __restrict__ WT) {
  const int blk = blockIdx.x, tid = threadIdx.x;
  if (blk < 6144) {
    int i = (blk * 256 + tid) * 8;
    const float4* p = (const float4*)(X + i);
    float4 a = p[0], b = p[1];
    union { u16 h[8]; uint4 v; } o;
    o.h[0] = f2bf(a.x); o.h[1] = f2bf(a.y); o.h[2] = f2bf(a.z); o.h[3] = f2bf(a.w);
    o.h[4] = f2bf(b.x); o.h[5] = f2bf(b.y); o.h[6] = f2bf(b.z); o.h[7] = f2bf(b.w);
    *(uint4*)(Xb + i) = o.v;
  } else {
    __shared__ float t[32][33];
    const int q = blk - 6144;
    const int w = q / 576, p = q % 576;
    const float* W = (w == 0) ? Wq : (w == 1) ? Wk : (w == 2) ? Wv : Wo;
    u16* D = WT + (size_t)w * 768 * 768;
    const int n0 = (p % 24) * 32, k0 = (p / 24) * 32;
    const int tx = tid & 31, ty = tid >> 5;
#pragma unroll
    for (int i = 0; i < 4; ++i)
      t[ty + i * 8][tx] = W[(size_t)(k0 + ty + i * 8) * 768 + n0 + tx];
    __syncthreads();
#pragma unroll
    for (int i = 0; i < 4; ++i)
      D[(size_t)(n0 + ty + i * 8) * 768 + k0 + tx] = f2bf(t[tx][ty + i * 8]);
  }
}

// ---------------- GEMM 256x192, BK=64, 1024 thr = 16 waves, 2-buffer ----
// C[m][n] = sum_k A[m][k] * BT[n][k] (+bias).
// 16 waves (4 wr x 4 wc), per-wave 64x64 output -> acc 64 VGPR -> 4 waves/SIMD
// (round-5's 8-wave/1-block config was stuck at 2 waves/SIMD = no latency
// hiding; MfmaUtil 26%). 2 LDS buffers (112 KB); per tile: vmcnt(0) drain of
// the 4-5 loads issued one full tile earlier (cheap), barrier, stage next
// tile early, then ds_read+MFMA. XOR-granule swizzle (proven 0 conflicts).
// Grid: MODE0 64x12=768 blocks (3.0/CU), MODE1 64x4=256 (1.0/CU); XCD-banded.
// MODE 0: QKV (N=2304): Q bf16 (scaled 1/8), K bf16, V bf16 transposed per (b,h)
// MODE 1: out-proj (N=768): fp32 + bias

#define STA(bu, t) do { _Pragma("unroll") for (int s_ = 0; s_ < 2; ++s_) { \
    const int r_ = s_ * 128 + srow; \
    gl_lds16(A + (size_t)(M0 + r_) * 768 + (t) * 64 + ((sg ^ (r_ & 7)) << 3), \
             &As[bu][r_ * 64 + sg * 8]); } } while (0)
#define STB(bu, t) do { \
    gl_lds16(BT + (size_t)(N0 + srow) * 768 + (t) * 64 + ((sg ^ (srow & 7)) << 3), \
             &Bs[bu][srow * 64 + sg * 8]); \
    if (srow < 64) { const int r_ = 128 + srow; \
      gl_lds16(BT + (size_t)(N0 + r_) * 768 + (t) * 64 + ((sg ^ (r_ & 7)) << 3), \
               &Bs[bu][r_ * 64 + sg * 8]); } } while (0)

template <int MODE>
__global__ __launch_bounds__(1024, 4)
void gemmN(const u16* __restrict__ A, const u16* __restrict__ BT,
           const float* __restrict__ b0, const float* __restrict__ b1,
           const float* __restrict__ b2,
           u16* __restrict__ oQ, u16* __restrict__ oK, u16* __restrict__ oV,
           float* __restrict__ oF, int nN) {
  constexpr int NT = 12; // K = 768 = 12 * 64
  __shared__ __align__(16) u16 As[2][256 * 64];
  __shared__ __align__(16) u16 Bs[2][192 * 64];
  const int tid = threadIdx.x;
  const int wave = tid >> 6, lane = tid & 63;
  const int lg = lane >> 4, l15 = lane & 15;
  const int wr = wave >> 2, wc = wave & 3;
  const int bi = blockIdx.x;
  const int j = bi >> 3;
  const int M0 = ((bi & 7) * 8 + j / nN) * 256; // XCD band of 8 M-tiles
  const int N0 = (j % nN) * 192;                // N-fastest within band
  const int srow = tid >> 3, sg = tid & 7;      // srow 0..127

  f32x4 acc[4][3] = {};

  STA(0, 0); STB(0, 0);

#pragma unroll
  for (int t = 0; t < NT; ++t) {
    WAITV(0);  // tile t's loads (issued one full tile ago) landed
    BARRIER();
    if (t + 1 < NT) { STA((t + 1) & 1, t + 1); STB((t + 1) & 1, t + 1); }
    const int bb = t & 1;
    __builtin_amdgcn_s_setprio(1);
    bf16x8 bfr[3][2];
#pragma unroll
    for (int nt = 0; nt < 3; ++nt)
#pragma unroll
      for (int kh = 0; kh < 2; ++kh) {
        const int row = wc * 48 + nt * 16 + l15;
        bfr[nt][kh] = *(const bf16x8*)&Bs[bb][row * 64 + (((kh * 4 + lg) ^ (row & 7)) << 3)];
      }
#pragma unroll
    for (int mt = 0; mt < 4; ++mt) {
      bf16x8 af[2];
#pragma unroll
      for (int kh = 0; kh < 2; ++kh) {
        const int row = wr * 64 + mt * 16 + l15;
        af[kh] = *(const bf16x8*)&As[bb][row * 64 + (((kh * 4 + lg) ^ (row & 7)) << 3)];
      }
#pragma unroll
      for (int nt = 0; nt < 3; ++nt)
#pragma unroll
        for (int kh = 0; kh < 2; ++kh)
          acc[mt][nt] = MFMA16(af[kh], bfr[nt][kh], acc[mt][nt]);
    }
    __builtin_amdgcn_s_setprio(0);
  }

#pragma unroll
  for (int mt = 0; mt < 4; ++mt) {
    const int r0 = M0 + wr * 64 + mt * 16 + lg * 4;
#pragma unroll
    for (int nt = 0; nt < 3; ++nt) {
      const int ng = N0 + wc * 48 + nt * 16 + l15;
      f32x4 v = acc[mt][nt];
      if (MODE == 1) {
        const float bb = b0[ng];
#pragma unroll
        for (int r = 0; r < 4; ++r)
          oF[(size_t)(r0 + r) * 768 + ng] = v[r] + bb;
      } else {
        const int mat = ng / 768;
        const int col = ng - mat * 768;
        const float bb = (mat == 0 ? b0 : (mat == 1 ? b1 : b2))[col];
        if (mat == 0) {
#pragma unroll
          for (int r = 0; r < 4; ++r)
            oQ[(size_t)(r0 + r) * 768 + col] = f2bf((v[r] + bb) * 0.125f);
        } else if (mat == 1) {
#pragma unroll
          for (int r = 0; r < 4; ++r)
            oK[(size_t)(r0 + r) * 768 + col] = f2bf(v[r] + bb);
        } else {
          const int hh = col >> 6, dd = col & 63;
#pragma unroll
          for (int r = 0; r < 4; ++r) {
            const int rr = r0 + r;
            const int bbx = rr >> 9, ss = rr & 511;
            oV[((size_t)(bbx * 12 + hh) * 64 + dd) * 512 + ss] = f2bf(v[r] + bb);
          }
        }
      }
    }
  }
}

// ---------------- causal flash attention, swapped-operand, 8 waves ----------
// grid: 1536 1-D; id -> qt = id/384 (q-tile of 128 rows), hb = id%384
// (h = hb%12, b = hb/12).  All qt of one (b,h) land on one XCD (id%8 = hb%8).
// Swapped QK^T: sc = mfma(K,Q) -> lane l15 owns q-row (wave*16+l15); regs hold
// keys t*16+lg*4+r.  Swapped PV: o = mfma(V^T,P) -> lane holds q-col, d rows.
// K/V: 3 LDS buffers, 1 barrier/tile, vmcnt(2) counted prefetch.
#define STG(bu, kt) do { \
    gl_lds16(Kg0 + (size_t)((kt) * 64 + srow) * 768 + sgr * 8, \
             &Ks[bu][srow * 64 + (tid & 7) * 8]); \
    gl_lds16(Vg0 + (size_t)srow * 512 + (kt) * 64 + sgr * 8, \
             &Vs[bu][srow * 64 + (tid & 7) * 8]); \
  } while (0)

__global__ __launch_bounds__(512, 2)
void flash(const u16* __restrict__ Q, const u16* __restrict__ K,
           const u16* __restrict__ V, u16* __restrict__ O) {
  __shared__ __align__(16) u16 Ks[3][4096]; // [64 key][64 d] swizzled granules
  __shared__ __align__(16) u16 Vs[3][4096]; // [64 d][64 key] swizzled granules
  __shared__ __align__(16) u32 Ps[8][16 * 36]; // per wave: [16 q][32+4 pad words]
  const int id = blockIdx.x;
  const int qt = id / 384, hb = id % 384;
  const int h = hb % 12, b = hb / 12;
  const int tid = threadIdx.x, wave = tid >> 6, lane = tid & 63;
  const int lg = lane >> 4, l15 = lane & 15;
  const int NT = 2 * qt + 2;
  const int srow = tid >> 3, sgr = (tid & 7) ^ (srow & 7);
  const int qbase = qt * 128 + wave * 16; // wave's first q row (within head)

  bf16x8 qf[2];
  {
    const u16* qp = Q + (size_t)(b * 512 + qbase + l15) * 768 + h * 64 + lg * 8;
    qf[0] = *(const bf16x8*)qp;
    qf[1] = *(const bf16x8*)(qp + 32);
  }
  f32x4 oacc[4] = {};
  float m_run = -1e30f, l_run = 0.f;
  const u16* Kg0 = K + (size_t)(b * 512) * 768 + h * 64;
  const u16* Vg0 = V + (size_t)(b * 12 + h) * 64 * 512;
  u32* pw = Ps[wave];

  STG(0, 0);
  STG(1, 1);
  for (int kt = 0; kt < NT; ++kt) {
    if (kt < NT - 1) { WAITV(2); } else { WAITV(0); }
    BARRIER(); // buf kt%3 ready; buf (kt+2)%3 == (kt-1)%3 free
    if (kt + 2 < NT) STG((kt + 2) % 3, kt + 2);
    const int bu = kt % 3;
    if (kt * 64 <= qbase + 15) { // wave has at least one unmasked key
      // ---- QK^T (swapped): rows=keys, cols=q ----
      f32x4 sc[4] = {};
#pragma unroll
      for (int kc = 0; kc < 2; ++kc)
#pragma unroll
        for (int t = 0; t < 4; ++t) {
          const int row = t * 16 + l15;
          bf16x8 kf = *(const bf16x8*)&Ks[bu][row * 64 + (((kc * 4 + lg) ^ (l15 & 7)) << 3)];
          sc[t] = MFMA16(kf, qf[kc], sc[t]);
        }
      if (kt * 64 + 63 > qbase) { // boundary tile: causal mask (key > q)
#pragma unroll
        for (int t = 0; t < 4; ++t)
#pragma unroll
          for (int r = 0; r < 4; ++r)
            if (kt * 64 + t * 16 + lg * 4 + r > qbase + l15) sc[t][r] = -1e30f;
      }
      // ---- online softmax: q-row is lane-local up to the 4 lg groups ----
      float pm = sc[0][0];
#pragma unroll
      for (int t = 0; t < 4; ++t)
#pragma unroll
        for (int r = 0; r < 4; ++r) pm = fmaxf(pm, sc[t][r]);
      pm = fmaxf(pm, __shfl_xor(pm, 16));
      pm = fmaxf(pm, __shfl_xor(pm, 32));
      if (__any(pm > m_run + 8.f)) { // defer-max: rescale only on real growth
        const float mn = fmaxf(m_run, pm);
        const float fs = __expf(m_run - mn);
        m_run = mn;
        l_run *= fs;
#pragma unroll
        for (int t = 0; t < 4; ++t)
#pragma unroll
          for (int r = 0; r < 4; ++r) oacc[t][r] *= fs;
      }
      float rs = 0.f;
#pragma unroll
      for (int t = 0; t < 4; ++t) {
        float p0 = __expf(sc[t][0] - m_run), p1 = __expf(sc[t][1] - m_run);
        float p2 = __expf(sc[t][2] - m_run), p3 = __expf(sc[t][3] - m_run);
        rs += (p0 + p1) + (p2 + p3);
        pw[l15 * 36 + t * 8 + lg * 2 + 0] = pk2(p0, p1);
        pw[l15 * 36 + t * 8 + lg * 2 + 1] = pk2(p2, p3);
      }
      rs += __shfl_xor(rs, 16);
      rs += __shfl_xor(rs, 32);
      l_run += rs;
      // ---- PV (swapped): A=V^T rows=d, B=P cols=q ----
#pragma unroll
      for (int kc = 0; kc < 2; ++kc) {
        bf16x8 pf = *(const bf16x8*)&pw[l15 * 36 + kc * 16 + lg * 4];
#pragma unroll
        for (int t = 0; t < 4; ++t) {
          const int row = t * 16 + l15;
          bf16x8 vf = *(const bf16x8*)&Vs[bu][row * 64 + (((kc * 4 + lg) ^ (l15 & 7)) << 3)];
          oacc[t] = MFMA16(vf, pf, oacc[t]);
        }
      }
    }
  }
  const float inv = 1.f / l_run;
  u16* op = O + (size_t)(b * 512 + qbase + l15) * 768 + h * 64;
#pragma unroll
  for (int t = 0; t < 4; ++t) {
    uint2 w;
    w.x = pk2(oacc[t][0] * inv, oacc[t][1] * inv);
    w.y = pk2(oacc[t][2] * inv, oacc[t][3] * inv);
    *(uint2*)(op + t * 16 + lg * 4) = w;
  }
}

extern "C" void kernel_launch(void* const* d_in, const int* in_sizes, int n_in,
                              void* d_out, int out_size, void* d_ws, size_t ws_size,
                              hipStream_t stream) {
  (void)in_sizes; (void)n_in; (void)out_size; (void)ws_size;
  const float* X  = (const float*)d_in[0];
  // d_in[1] = causal mask: exactly triu(-1e9) -> equivalent to hard causal masking; unused.
  const float* Wq = (const float*)d_in[2];
  const float* bq = (const float*)d_in[3];
  const float* Wk = (const float*)d_in[4];
  const float* bk = (const float*)d_in[5];
  const float* Wv = (const float*)d_in[6];
  const float* bv = (const float*)d_in[7];
  const float* Wo = (const float*)d_in[8];
  const float* bo = (const float*)d_in[9];
  float* out = (float*)d_out;

  const size_t NME = (size_t)16384 * 768;
  u16* Xb  = (u16*)d_ws;        // bf16 X, later reused as attention output
  u16* Qs  = Xb + NME;
  u16* Kb  = Qs + NME;
  u16* Vt  = Kb + NME;          // [b*12+h][64][512]
  u16* WT  = Vt + NME;          // [3072][768]  (WqT | WkT | WvT | WoT)
  u16* WoT = WT + (size_t)2304 * 768;
  u16* Ao  = Xb;

  prep<<<8448, 256, 0, stream>>>(X, Xb, Wq, Wk, Wv, Wo, WT);
  gemmN<0><<<768, 1024, 0, stream>>>(Xb, WT, bq, bk, bv, Qs, Kb, Vt, nullptr, 12);
  flash<<<1536, 512, 0, stream>>>(Qs, Kb, Vt, Ao);
  gemmN<1><<<256, 1024, 0, stream>>>(Ao, WoT, bo, nullptr, nullptr,
                                     nullptr, nullptr, nullptr, out, 4);
}